// Round 1
// baseline (47.247 us; speedup 1.0000x reference)
//
#include <hip/hip_runtime.h>

#define S_GRID 7
#define NCOL 90            // 5*B + C = 10 + 80
#define LAMBDA_COORD 5.0f
#define LAMBDA_NOOBJ 0.5f

__global__ __launch_bounds__(256) void yolo_cell_kernel(
    const float* __restrict__ pred,
    const float* __restrict__ targ,
    float* __restrict__ partials,
    int ncells)
{
    const float inv_s = 1.0f / 7.0f;
    int cell = blockIdx.x * blockDim.x + threadIdx.x;

    float loss = 0.0f;
    if (cell < ncells) {
        const float2* p2 = reinterpret_cast<const float2*>(pred + (size_t)cell * NCOL);
        const float2* t2 = reinterpret_cast<const float2*>(targ + (size_t)cell * NCOL);

        // first 10 columns (box data) of pred and target
        float p[10], t[10];
#pragma unroll
        for (int i = 0; i < 5; ++i) {
            float2 a = p2[i];
            float2 b = t2[i];
            p[2*i] = a.x; p[2*i+1] = a.y;
            t[2*i] = b.x; t[2*i+1] = b.y;
        }

        // class loss sum over columns 10..89
        float cls = 0.0f;
#pragma unroll 8
        for (int i = 5; i < 45; ++i) {
            float2 a = p2[i];
            float2 b = t2[i];
            float dx = a.x - b.x;
            float dy = a.y - b.y;
            cls += dx * dx + dy * dy;
        }

        float conf_t = t[4];
        float coord_m = (conf_t > 0.0f) ? 1.0f : 0.0f;
        float noobj_m = (conf_t == 0.0f) ? 1.0f : 0.0f;

        // noobj confidence loss: columns 4 and 9
        float d4 = p[4] - t[4];
        float d9 = p[9] - t[9];
        float noobj = noobj_m * (d4 * d4 + d9 * d9);

        // target box (first box) transform
        float tax = t[0] * inv_s - 0.5f * t[2];
        float tay = t[1] * inv_s - 0.5f * t[3];
        float tbx = tax * inv_s + 0.5f * t[2];
        float tby = tay * inv_s + 0.5f * t[3];
        float t_area = (tbx - tax) * (tby - tay);

        // pred boxes transform + IoU vs target box
        float pax[2], pay[2], pbx[2], pby[2], iou[2];
#pragma unroll
        for (int b = 0; b < 2; ++b) {
            const float* q = p + 5 * b;
            float ax = q[0] * inv_s - 0.5f * q[2];
            float ay = q[1] * inv_s - 0.5f * q[3];
            float bx = ax * inv_s + 0.5f * q[2];
            float by = ay * inv_s + 0.5f * q[3];
            pax[b] = ax; pay[b] = ay; pbx[b] = bx; pby[b] = by;
            float tlx = fmaxf(ax, tax);
            float tly = fmaxf(ay, tay);
            float brx = fminf(bx, tbx);
            float bry = fminf(by, tby);
            float w = fmaxf(brx - tlx, 0.0f);
            float h = fmaxf(bry - tly, 0.0f);
            float inter = w * h;
            float parea = (bx - ax) * (by - ay);
            iou[b] = inter / (parea + t_area - inter);
        }

        // argmax with first-max-on-tie semantics
        int idx = (iou[1] > iou[0]) ? 1 : 0;
        float tiou = idx ? iou[1] : iou[0];

        // selected pred box (transformed) + its confidence
        float psx = idx ? pax[1] : pax[0];
        float psy = idx ? pay[1] : pay[0];
        float psw = idx ? pbx[1] : pbx[0];
        float psh = idx ? pby[1] : pby[0];
        float psc = idx ? p[9] : p[4];

        // selected target box: transformed first box if idx==0, RAW second box if idx==1
        float tsx, tsy, tsw, tsh;
        if (idx == 0) { tsx = tax; tsy = tay; tsw = tbx; tsh = tby; }
        else          { tsx = t[5]; tsy = t[6]; tsw = t[7]; tsh = t[8]; }

        float dx = psx - tsx;
        float dy = psy - tsy;
        float dw = psw - tsw;
        float dh = psh - tsh;
        float xy = dx * dx + dy * dy;
        float wh = dw * dw + dh * dh;
        float dc = psc - tiou;

        float gated = LAMBDA_COORD * (xy + wh) + dc * dc + cls;
        loss = coord_m * gated + LAMBDA_NOOBJ * noobj;
    }

    // wave64 reduce
#pragma unroll
    for (int off = 32; off > 0; off >>= 1)
        loss += __shfl_down(loss, off, 64);

    __shared__ float red[4];
    int lane = threadIdx.x & 63;
    int wid  = threadIdx.x >> 6;
    if (lane == 0) red[wid] = loss;
    __syncthreads();
    if (threadIdx.x == 0) {
        partials[blockIdx.x] = red[0] + red[1] + red[2] + red[3];
    }
}

__global__ __launch_bounds__(256) void yolo_reduce_kernel(
    const float* __restrict__ partials, int n, float* __restrict__ out)
{
    float s = 0.0f;
    for (int i = threadIdx.x; i < n; i += blockDim.x)
        s += partials[i];
#pragma unroll
    for (int off = 32; off > 0; off >>= 1)
        s += __shfl_down(s, off, 64);

    __shared__ float red[4];
    int lane = threadIdx.x & 63;
    int wid  = threadIdx.x >> 6;
    if (lane == 0) red[wid] = s;
    __syncthreads();
    if (threadIdx.x == 0) {
        float tot = red[0] + red[1] + red[2] + red[3];
        out[0] = tot * (1.0f / 4096.0f);
    }
}

extern "C" void kernel_launch(void* const* d_in, const int* in_sizes, int n_in,
                              void* d_out, int out_size, void* d_ws, size_t ws_size,
                              hipStream_t stream) {
    const float* pred = (const float*)d_in[0];
    const float* targ = (const float*)d_in[1];
    float* out = (float*)d_out;

    int ncells = in_sizes[0] / NCOL;             // 4096*7*7 = 200704
    int block = 256;
    int nblocks = (ncells + block - 1) / block;  // 784

    float* partials = (float*)d_ws;              // 784 floats = 3136 B scratch

    yolo_cell_kernel<<<nblocks, block, 0, stream>>>(pred, targ, partials, ncells);
    yolo_reduce_kernel<<<1, block, 0, stream>>>(partials, nblocks, out);
}

// Round 2
// 34.726 us; speedup vs baseline: 1.3606x; 1.3606x over previous
//
#include <hip/hip_runtime.h>

#define NCOL 90            // 5*B + C = 10 + 80
#define LAMBDA_COORD 5.0f
#define LAMBDA_NOOBJ 0.5f

// 4 lanes per cell. Lane r sweeps float2 pairs at columns 2r + 8k (all even
// cols 0..88 covered exactly once across the group). Class cols (>=10)
// accumulate per-lane; box cols 0..9 re-read by all 4 lanes (L1 broadcast).
__global__ __launch_bounds__(256) void yolo_cell_kernel(
    const float* __restrict__ pred,
    const float* __restrict__ targ,
    float* __restrict__ partials,
    int ncells)
{
    const float inv_s = 1.0f / 7.0f;
    int tid  = blockIdx.x * blockDim.x + threadIdx.x;
    int cell = tid >> 2;
    int r    = tid & 3;

    float loss = 0.0f;
    if (cell < ncells) {
        const float* pc = pred + (size_t)cell * NCOL;
        const float* tc = targ + (size_t)cell * NCOL;

        // ---- coalesced class sweep ----
        float cls_acc = 0.0f;
#pragma unroll
        for (int k = 0; k < 12; ++k) {
            int col = 2 * r + 8 * k;
            if (col < NCOL) {
                float2 a = *reinterpret_cast<const float2*>(pc + col);
                float2 b = *reinterpret_cast<const float2*>(tc + col);
                if (col >= 10) {   // pairs never straddle the 10-boundary
                    float dx = a.x - b.x;
                    float dy = a.y - b.y;
                    cls_acc += dx * dx + dy * dy;
                }
            }
        }

        // ---- box columns 0..9 (all 4 lanes redundantly; cache-hot) ----
        float p[10], t[10];
#pragma unroll
        for (int i = 0; i < 5; ++i) {
            float2 a = *reinterpret_cast<const float2*>(pc + 2 * i);
            float2 b = *reinterpret_cast<const float2*>(tc + 2 * i);
            p[2*i] = a.x; p[2*i+1] = a.y;
            t[2*i] = b.x; t[2*i+1] = b.y;
        }

        float conf_t  = t[4];
        float coord_m = (conf_t > 0.0f) ? 1.0f : 0.0f;
        float noobj_m = (conf_t == 0.0f) ? 1.0f : 0.0f;

        // noobj confidence loss: cols 4 and 9
        float d4 = p[4] - t[4];
        float d9 = p[9] - t[9];
        float noobj = noobj_m * (d4 * d4 + d9 * d9);

        // target box (first box) transform
        float tax = t[0] * inv_s - 0.5f * t[2];
        float tay = t[1] * inv_s - 0.5f * t[3];
        float tbx = tax * inv_s + 0.5f * t[2];
        float tby = tay * inv_s + 0.5f * t[3];
        float t_area = (tbx - tax) * (tby - tay);

        // pred boxes transform + IoU vs target box
        float pax[2], pay[2], pbx[2], pby[2], iou[2];
#pragma unroll
        for (int b = 0; b < 2; ++b) {
            const float* q = p + 5 * b;
            float ax = q[0] * inv_s - 0.5f * q[2];
            float ay = q[1] * inv_s - 0.5f * q[3];
            float bx = ax * inv_s + 0.5f * q[2];
            float by = ay * inv_s + 0.5f * q[3];
            pax[b] = ax; pay[b] = ay; pbx[b] = bx; pby[b] = by;
            float tlx = fmaxf(ax, tax);
            float tly = fmaxf(ay, tay);
            float brx = fminf(bx, tbx);
            float bry = fminf(by, tby);
            float w = fmaxf(brx - tlx, 0.0f);
            float h = fmaxf(bry - tly, 0.0f);
            float inter = w * h;
            float parea = (bx - ax) * (by - ay);
            iou[b] = inter / (parea + t_area - inter);
        }

        // argmax (first-max-on-tie)
        int idx = (iou[1] > iou[0]) ? 1 : 0;
        float tiou = idx ? iou[1] : iou[0];

        float psx = idx ? pax[1] : pax[0];
        float psy = idx ? pay[1] : pay[0];
        float psw = idx ? pbx[1] : pbx[0];
        float psh = idx ? pby[1] : pby[0];
        float psc = idx ? p[9] : p[4];

        // selected target: transformed first box if idx==0, RAW second box else
        float tsx, tsy, tsw, tsh;
        if (idx == 0) { tsx = tax; tsy = tay; tsw = tbx; tsh = tby; }
        else          { tsx = t[5]; tsy = t[6]; tsw = t[7]; tsh = t[8]; }

        float dx = psx - tsx;
        float dy = psy - tsy;
        float dw = psw - tsw;
        float dh = psh - tsh;
        float xy = dx * dx + dy * dy;
        float wh = dw * dw + dh * dh;
        float dc = psc - tiou;

        float cell_term = coord_m * (LAMBDA_COORD * (xy + wh) + dc * dc)
                        + LAMBDA_NOOBJ * noobj;

        // lane contribution: own gated class partial; cell term only on r==0
        loss = coord_m * cls_acc + ((r == 0) ? cell_term : 0.0f);
    }

    // wave64 reduce
#pragma unroll
    for (int off = 32; off > 0; off >>= 1)
        loss += __shfl_down(loss, off, 64);

    __shared__ float red[4];
    int lane = threadIdx.x & 63;
    int wid  = threadIdx.x >> 6;
    if (lane == 0) red[wid] = loss;
    __syncthreads();
    if (threadIdx.x == 0) {
        partials[blockIdx.x] = red[0] + red[1] + red[2] + red[3];
    }
}

__global__ __launch_bounds__(256) void yolo_reduce_kernel(
    const float* __restrict__ partials, int n, float* __restrict__ out)
{
    float s = 0.0f;
    for (int i = threadIdx.x; i < n; i += blockDim.x)
        s += partials[i];
#pragma unroll
    for (int off = 32; off > 0; off >>= 1)
        s += __shfl_down(s, off, 64);

    __shared__ float red[4];
    int lane = threadIdx.x & 63;
    int wid  = threadIdx.x >> 6;
    if (lane == 0) red[wid] = s;
    __syncthreads();
    if (threadIdx.x == 0) {
        float tot = red[0] + red[1] + red[2] + red[3];
        out[0] = tot * (1.0f / 4096.0f);
    }
}

extern "C" void kernel_launch(void* const* d_in, const int* in_sizes, int n_in,
                              void* d_out, int out_size, void* d_ws, size_t ws_size,
                              hipStream_t stream) {
    const float* pred = (const float*)d_in[0];
    const float* targ = (const float*)d_in[1];
    float* out = (float*)d_out;

    int ncells   = in_sizes[0] / NCOL;                 // 4096*7*7 = 200704
    int block    = 256;
    int nthreads = ncells * 4;                         // 4 lanes per cell
    int nblocks  = (nthreads + block - 1) / block;     // 3136

    float* partials = (float*)d_ws;                    // 3136 floats scratch

    yolo_cell_kernel<<<nblocks, block, 0, stream>>>(pred, targ, partials, ncells);
    yolo_reduce_kernel<<<1, block, 0, stream>>>(partials, nblocks, out);
}

// Round 3
// 31.646 us; speedup vs baseline: 1.4930x; 1.0973x over previous
//
#include <hip/hip_runtime.h>

#define NCOL 90                     // 5*B + C = 10 + 80
#define CB 64                       // cells per block
#define CHUNK (CB * NCOL)           // 5760 floats per array per block (23040 B)
#define LAMBDA_COORD 5.0f
#define LAMBDA_NOOBJ 0.5f

typedef const __attribute__((address_space(1))) void* gas_ptr;
typedef __attribute__((address_space(3))) void* las_ptr;

__device__ __forceinline__ void dma16(const float* g, float* l) {
    __builtin_amdgcn_global_load_lds((gas_ptr)g, (las_ptr)l, 16, 0, 0);
}
__device__ __forceinline__ void dma4(const float* g, float* l) {
    __builtin_amdgcn_global_load_lds((gas_ptr)g, (las_ptr)l, 4, 0, 0);
}

// Block stages 64 cells of pred+targ (23040 B each) into LDS via
// global_load_lds DMA (coalesced 16 B/lane, all ops in flight), then
// 4 lanes/cell compute the per-cell YOLO loss from LDS.
__global__ __launch_bounds__(256) void yolo_cell_kernel(
    const float* __restrict__ pred,
    const float* __restrict__ targ,
    float* __restrict__ partials)
{
    __shared__ float lds[2 * CHUNK];          // 46080 B

    const float inv_s = 1.0f / 7.0f;
    const int wave = threadIdx.x >> 6;
    const int lane = threadIdx.x & 63;

    const float* psrc = pred + (size_t)blockIdx.x * CHUNK;
    const float* tsrc = targ + (size_t)blockIdx.x * CHUNK;

    // Combined LDS region: floats [0,5760) = pred chunk, [5760,11520) = targ.
    // 45 x 1KB slices; slice 22 straddles the array boundary -> special-cased.
    for (int s = wave; s < 45; s += 4) {
        if (s == 22) continue;
        int off = s * 256;                    // float offset in combined region
        const float* src = (s < 22) ? (psrc + off) : (tsrc + (off - CHUNK));
        dma16(src + lane * 4, lds + off);
    }
    // tail: pred floats [5632,5760) and targ floats [0,128), one 4B op/wave
    {
        const float* src;
        int off;
        switch (wave) {
            case 0:  src = psrc + 5632; off = 5632; break;
            case 1:  src = psrc + 5696; off = 5696; break;
            case 2:  src = tsrc + 0;    off = 5760; break;
            default: src = tsrc + 64;   off = 5824; break;
        }
        dma4(src + lane, lds + off);
    }
    asm volatile("s_waitcnt vmcnt(0)" ::: "memory");
    __syncthreads();

    // ---- compute: 4 lanes per cell, from LDS ----
    const int g = threadIdx.x >> 2;           // cell within chunk, 0..63
    const int r = threadIdx.x & 3;
    const float* lp = lds + g * NCOL;
    const float* lt = lds + CHUNK + g * NCOL;

    // class sweep: lane r covers float2s at cols 2r+8k (cols >= 10)
    float cls_acc = 0.0f;
#pragma unroll
    for (int k = 0; k < 12; ++k) {
        int col = 2 * r + 8 * k;
        if (col >= 10 && col < NCOL) {
            float2 a = *reinterpret_cast<const float2*>(lp + col);
            float2 b = *reinterpret_cast<const float2*>(lt + col);
            float dx = a.x - b.x;
            float dy = a.y - b.y;
            cls_acc += dx * dx + dy * dy;
        }
    }

    // box columns 0..9 (broadcast reads within 4-lane group)
    float p[10], t[10];
#pragma unroll
    for (int i = 0; i < 10; ++i) { p[i] = lp[i]; t[i] = lt[i]; }

    float conf_t  = t[4];
    float coord_m = (conf_t > 0.0f) ? 1.0f : 0.0f;
    float noobj_m = (conf_t == 0.0f) ? 1.0f : 0.0f;

    // noobj confidence loss: cols 4 and 9
    float d4 = p[4] - t[4];
    float d9 = p[9] - t[9];
    float noobj = noobj_m * (d4 * d4 + d9 * d9);

    // target box (first box) transform
    float tax = t[0] * inv_s - 0.5f * t[2];
    float tay = t[1] * inv_s - 0.5f * t[3];
    float tbx = tax * inv_s + 0.5f * t[2];
    float tby = tay * inv_s + 0.5f * t[3];
    float t_area = (tbx - tax) * (tby - tay);

    // pred boxes transform + IoU vs target box
    float pax[2], pay[2], pbx[2], pby[2], iou[2];
#pragma unroll
    for (int b = 0; b < 2; ++b) {
        const float* q = p + 5 * b;
        float ax = q[0] * inv_s - 0.5f * q[2];
        float ay = q[1] * inv_s - 0.5f * q[3];
        float bx = ax * inv_s + 0.5f * q[2];
        float by = ay * inv_s + 0.5f * q[3];
        pax[b] = ax; pay[b] = ay; pbx[b] = bx; pby[b] = by;
        float tlx = fmaxf(ax, tax);
        float tly = fmaxf(ay, tay);
        float brx = fminf(bx, tbx);
        float bry = fminf(by, tby);
        float w = fmaxf(brx - tlx, 0.0f);
        float h = fmaxf(bry - tly, 0.0f);
        float inter = w * h;
        float parea = (bx - ax) * (by - ay);
        iou[b] = inter / (parea + t_area - inter);
    }

    // argmax (first-max-on-tie)
    int idx = (iou[1] > iou[0]) ? 1 : 0;
    float tiou = idx ? iou[1] : iou[0];

    float psx = idx ? pax[1] : pax[0];
    float psy = idx ? pay[1] : pay[0];
    float psw = idx ? pbx[1] : pbx[0];
    float psh = idx ? pby[1] : pby[0];
    float psc = idx ? p[9] : p[4];

    // selected target: transformed first box if idx==0, RAW second box else
    float tsx, tsy, tsw, tsh;
    if (idx == 0) { tsx = tax; tsy = tay; tsw = tbx; tsh = tby; }
    else          { tsx = t[5]; tsy = t[6]; tsw = t[7]; tsh = t[8]; }

    float dx = psx - tsx;
    float dy = psy - tsy;
    float dw = psw - tsw;
    float dh = psh - tsh;
    float xy = dx * dx + dy * dy;
    float wh = dw * dw + dh * dh;
    float dc = psc - tiou;

    float cell_term = coord_m * (LAMBDA_COORD * (xy + wh) + dc * dc)
                    + LAMBDA_NOOBJ * noobj;

    float loss = coord_m * cls_acc + ((r == 0) ? cell_term : 0.0f);

    // wave64 reduce
#pragma unroll
    for (int off = 32; off > 0; off >>= 1)
        loss += __shfl_down(loss, off, 64);

    __shared__ float red[4];
    if (lane == 0) red[wave] = loss;
    __syncthreads();
    if (threadIdx.x == 0) {
        partials[blockIdx.x] = red[0] + red[1] + red[2] + red[3];
    }
}

__global__ __launch_bounds__(256) void yolo_reduce_kernel(
    const float* __restrict__ partials, int n, float* __restrict__ out)
{
    float s = 0.0f;
    for (int i = threadIdx.x; i < n; i += blockDim.x)
        s += partials[i];
#pragma unroll
    for (int off = 32; off > 0; off >>= 1)
        s += __shfl_down(s, off, 64);

    __shared__ float red[4];
    int lane = threadIdx.x & 63;
    int wid  = threadIdx.x >> 6;
    if (lane == 0) red[wid] = s;
    __syncthreads();
    if (threadIdx.x == 0) {
        float tot = red[0] + red[1] + red[2] + red[3];
        out[0] = tot * (1.0f / 4096.0f);
    }
}

extern "C" void kernel_launch(void* const* d_in, const int* in_sizes, int n_in,
                              void* d_out, int out_size, void* d_ws, size_t ws_size,
                              hipStream_t stream) {
    const float* pred = (const float*)d_in[0];
    const float* targ = (const float*)d_in[1];
    float* out = (float*)d_out;

    int ncells  = in_sizes[0] / NCOL;        // 4096*7*7 = 200704
    int nblocks = ncells / CB;               // 3136 (exact)

    float* partials = (float*)d_ws;          // 3136 floats scratch

    yolo_cell_kernel<<<nblocks, 256, 0, stream>>>(pred, targ, partials);
    yolo_reduce_kernel<<<1, 256, 0, stream>>>(partials, nblocks, out);
}